// Round 9
// baseline (194.806 us; speedup 1.0000x reference)
//
#include <hip/hip_runtime.h>
#include <math.h>

// Problem constants (fixed by setup_inputs)
#define Nn 4
#define Ll 4096
#define Ss 256
#define Cc 256
#define FC 8
#define SC 32

#define ASTR 68                         // A-tile LDS stride (64 rows + pad)
#define BSTR 132                        // B-tile LDS stride (128 rows + pad)
#define PHI(k) ((((k) >> 3) & 3) << 2)  // row-XOR swizzle (const per k-octet)

typedef __attribute__((ext_vector_type(8))) short short8;   // 8 bf16 frag
typedef __attribute__((ext_vector_type(4))) float f32x4;    // MFMA acc

__device__ __forceinline__ unsigned short f2bf(float x) {   // RTNE f32->bf16
  unsigned int u = __float_as_uint(x);
  return (unsigned short)((u + 0x7FFFu + ((u >> 16) & 1u)) >> 16);
}

// ---------------------------------------------------------------------------
// k-major fp32 GEMM tile, 64x128, 128 threads (2 waves), thread 8x8.
// Thread rows {4tr+i, 32+4tr+i} (tr=t>>4 in [0,8)), cols {cb0+4tc+c,
// cb0+64+4tc+c} (tc=t&15). LDS word (r,k): A at k*ASTR + (r^PHI(k)),
// B at k*BSTR + (r^PHI(k)). Staging: thread owns one 4x4 A block and two
// 4x4 B blocks -> register transpose -> ds_write_b128. kt+1 global prefetch
// issued AFTER the post-staging barrier (round-7 proven barrier-drain fix).
// ---------------------------------------------------------------------------
__device__ __forceinline__ void gemm_tile64(
    const float* __restrict__ A, const float* __restrict__ W,
    const float* __restrict__ bias, size_t row0, int cb0,
    float* __restrict__ As, float* __restrict__ Bs, int t, float acc[8][8]) {
  int tc = t & 15, tr = t >> 4;        // tr in [0,8)
  int jq = t & 7, r0s = 4 * (t >> 3);  // t>>3 in [0,16): rows r0s..r0s+3
  int phS = ((jq >> 1) & 3) << 2;      // PHI(4jq+q), q<4
  int woffA = (4 * jq) * ASTR + (r0s ^ phS);
  int woffB = (4 * jq) * BSTR + (r0s ^ phS);

  float4 bb0 = *(const float4*)&bias[cb0 + 4 * tc];
  float4 bb1 = *(const float4*)&bias[cb0 + 64 + 4 * tc];
#pragma unroll
  for (int i = 0; i < 8; i++) {
    acc[i][0] = bb0.x; acc[i][1] = bb0.y; acc[i][2] = bb0.z; acc[i][3] = bb0.w;
    acc[i][4] = bb1.x; acc[i][5] = bb1.y; acc[i][6] = bb1.z; acc[i][7] = bb1.w;
  }

  float4 pa[4], pb0[4], pb1[4];
#pragma unroll
  for (int i = 0; i < 4; i++) {
    pa[i]  = *(const float4*)(A + (row0 + r0s + i) * Cc + 4 * jq);
    pb0[i] = *(const float4*)(W + (size_t)(cb0 + r0s + i) * Cc + 4 * jq);
    pb1[i] = *(const float4*)(W + (size_t)(cb0 + 64 + r0s + i) * Cc + 4 * jq);
  }

  for (int kt = 0; kt < 8; kt++) {
    __syncthreads();  // reads of previous tile done before overwrite
#pragma unroll
    for (int q = 0; q < 4; q++) {
      float4 wa, w0, w1;
      wa.x = ((const float*)&pa[0])[q];  wa.y = ((const float*)&pa[1])[q];
      wa.z = ((const float*)&pa[2])[q];  wa.w = ((const float*)&pa[3])[q];
      w0.x = ((const float*)&pb0[0])[q]; w0.y = ((const float*)&pb0[1])[q];
      w0.z = ((const float*)&pb0[2])[q]; w0.w = ((const float*)&pb0[3])[q];
      w1.x = ((const float*)&pb1[0])[q]; w1.y = ((const float*)&pb1[1])[q];
      w1.z = ((const float*)&pb1[2])[q]; w1.w = ((const float*)&pb1[3])[q];
      *(float4*)&As[woffA + q * ASTR] = wa;
      *(float4*)&Bs[woffB + q * BSTR] = w0;
      *(float4*)&Bs[woffB + 64 + q * BSTR] = w1;
    }
    __syncthreads();  // staging visible
    if (kt < 7) {     // prefetch AFTER barrier: hides behind compute
#pragma unroll
      for (int i = 0; i < 4; i++) {
        pa[i]  = *(const float4*)(A + (row0 + r0s + i) * Cc + (kt + 1) * 32 + 4 * jq);
        pb0[i] = *(const float4*)(W + (size_t)(cb0 + r0s + i) * Cc + (kt + 1) * 32 + 4 * jq);
        pb1[i] = *(const float4*)(W + (size_t)(cb0 + 64 + r0s + i) * Cc + (kt + 1) * 32 + 4 * jq);
      }
    }

    int ia0 = 4 * tr, ib0 = 4 * tc;
#pragma unroll 8
    for (int k = 0; k < 32; k++) {
      int ph = PHI(k);
      int ja = ia0 ^ ph, jb = ib0 ^ ph;
      float4 a0 = *(const float4*)&As[k * ASTR + ja];
      float4 a1 = *(const float4*)&As[k * ASTR + 32 + ja];
      float4 b0 = *(const float4*)&Bs[k * BSTR + jb];
      float4 b1 = *(const float4*)&Bs[k * BSTR + 64 + jb];
      const float* af0 = (const float*)&a0;
      const float* af1 = (const float*)&a1;
      const float* bf0 = (const float*)&b0;
      const float* bf1 = (const float*)&b1;
#pragma unroll
      for (int i = 0; i < 4; i++) {
#pragma unroll
        for (int c = 0; c < 4; c++) {
          acc[i][c]         = fmaf(af0[i], bf0[c], acc[i][c]);
          acc[i][c + 4]     = fmaf(af0[i], bf1[c], acc[i][c + 4]);
          acc[i + 4][c]     = fmaf(af1[i], bf0[c], acc[i + 4][c]);
          acc[i + 4][c + 4] = fmaf(af1[i], bf1[c], acc[i + 4][c + 4]);
        }
      }
    }
  }
}

// ---------------------------------------------------------------------------
// Fused kernel 1. Blocks 0..511: x0p = x0 @ W0^T + b0 -> xn (64-row tiles).
// Blocks 512..575: c1 = center1 @ W1^T + b1 (M=1024,N=512) + split/norm
// epilogue -> cpn (l2-normalized point half), cval (raw value half).
// ---------------------------------------------------------------------------
__global__ __launch_bounds__(128) void x0p_c1_k(
    const float* __restrict__ x0, const float* __restrict__ W0,
    const float* __restrict__ b0, const float* __restrict__ center1,
    const float* __restrict__ W1, const float* __restrict__ b1,
    float* __restrict__ xn, float* __restrict__ cpn, float* __restrict__ cval) {
  __shared__ float As[32 * ASTR];  //  8.7 KB
  __shared__ float Bs[32 * BSTR];  // 16.9 KB
  int t = threadIdx.x;
  int tc = t & 15, tr = t >> 4;
  int b = blockIdx.x;
  float acc[8][8];

  if (b < 512) {
    size_t row0 = (size_t)(b >> 1) * 64;
    int cb0 = (b & 1) * 128;
    gemm_tile64(x0, W0, b0, row0, cb0, As, Bs, t, acc);
#pragma unroll
    for (int i = 0; i < 8; i++) {
      int r = (i < 4) ? (4 * tr + i) : (32 + 4 * tr + (i - 4));
      float4 o0, o1;
      o0.x = acc[i][0]; o0.y = acc[i][1]; o0.z = acc[i][2]; o0.w = acc[i][3];
      o1.x = acc[i][4]; o1.y = acc[i][5]; o1.z = acc[i][6]; o1.w = acc[i][7];
      float* cr = xn + (row0 + r) * Cc + cb0;
      *(float4*)(cr + 4 * tc) = o0;
      *(float4*)(cr + 64 + 4 * tc) = o1;
    }
  } else {
    int b2 = b - 512;
    size_t row0 = (size_t)(b2 >> 2) * 64;  // M=1024 (n*256+s)
    int cb0 = (b2 & 3) * 128;              // N=512
    gemm_tile64(center1, W1, b1, row0, cb0, As, Bs, t, acc);
    // cols {cb0+4tc+c} (fiber fb) / {cb0+64+4tc+c} (fiber fb+1);
    // q = 4tc+c in 0..63; point iff q<32 <=> tc<8.
    int fb = cb0 >> 6;
#pragma unroll
    for (int i = 0; i < 8; i++) {
      int r = (i < 4) ? (4 * tr + i) : (32 + 4 * tr + (i - 4));
      int crow = (int)row0 + r;
      int nI = crow >> 8, s = crow & 255;
#pragma unroll
      for (int h = 0; h < 2; h++) {
        float s0 = acc[i][4 * h + 0], s1 = acc[i][4 * h + 1];
        float s2 = acc[i][4 * h + 2], s3 = acc[i][4 * h + 3];
        float ss = s0 * s0 + s1 * s1 + s2 * s2 + s3 * s3;
        ss += __shfl_xor(ss, 1, 64);
        ss += __shfl_xor(ss, 2, 64);
        ss += __shfl_xor(ss, 4, 64);  // sums the tc-octet (point lanes tc<8)
        float rin = 1.f / fmaxf(sqrtf(ss), 1e-12f);
        int f = fb + h;
        size_t base = (((size_t)nI * FC + f) * Ss + s) * SC;
        if (tc < 8) {
          float4 o; o.x = s0 * rin; o.y = s1 * rin; o.z = s2 * rin; o.w = s3 * rin;
          *(float4*)&cpn[base + 4 * tc] = o;
        } else {
          float4 o; o.x = s0; o.y = s1; o.z = s2; o.w = s3;
          *(float4*)&cval[base + 4 * (tc - 8)] = o;
        }
      }
    }
  }
}

// ---------------------------------------------------------------------------
// sim: per block one (n,f), 64 l-rows; centers processed as TWO tiles of 128
// looped in-block (LDS 25.6 KB -> ~6 resident blocks/CU). 128 threads,
// thread 8 rows {4tr+i, 32+4tr+i} x 8 centers {4tc+c, 64+4tc+c} per tile;
// per k: 4 ds_read_b128 + 64 fmaf (read-then-use). X rows l2-normalized at
// staging. Argmax of a*sim+b folded across tiles in-thread (s increasing ->
// strict > keeps first max), then 16-lane shfl_xor reduce (min-index tie).
// Gather c_value, scale by sigmoid(max), write dispatched IN PLACE over xn.
// ---------------------------------------------------------------------------
__global__ __launch_bounds__(128) void sim_k(
    float* __restrict__ xn, const float* __restrict__ cpn,
    const float* __restrict__ cval, const float* __restrict__ alphap,
    const float* __restrict__ betap) {
  __shared__ float Xs[32 * ASTR];  //  8.7 KB (rows 0..63)
  __shared__ float Cs[32 * BSTR];  // 16.9 KB (128 centers per tile)
  int t = threadIdx.x;
  int tc = t & 15, tr = t >> 4;    // tr in [0,8)
  int lt = blockIdx.x & 63;
  int nf = blockIdx.x >> 6;        // 0..31
  int f = nf & 7, nI = nf >> 3;
  int l0 = lt * 64;
  const float* cp = cpn + (size_t)nf * Ss * SC;

  // stage x rows 64x32, l2-normalized (8-lane shfl per row)
  {
    int jq = t & 7, r0 = 4 * (t >> 3);  // rows r0..r0+3, r0 in {0..60}
    int ph = ((jq >> 1) & 3) << 2;
    float4 v[4];
    float ssq[4];
#pragma unroll
    for (int i = 0; i < 4; i++) {
      v[i] = *(const float4*)(xn + ((size_t)nI * Ll + l0 + r0 + i) * Cc + f * SC + 4 * jq);
      ssq[i] = v[i].x * v[i].x + v[i].y * v[i].y + v[i].z * v[i].z + v[i].w * v[i].w;
    }
#pragma unroll
    for (int m = 1; m <= 4; m <<= 1)
#pragma unroll
      for (int i = 0; i < 4; i++) ssq[i] += __shfl_xor(ssq[i], m, 64);
#pragma unroll
    for (int i = 0; i < 4; i++) {
      float rin = 1.f / fmaxf(sqrtf(ssq[i]), 1e-12f);
      v[i].x *= rin; v[i].y *= rin; v[i].z *= rin; v[i].w *= rin;
    }
#pragma unroll
    for (int q = 0; q < 4; q++) {
      float4 w;
      w.x = ((const float*)&v[0])[q]; w.y = ((const float*)&v[1])[q];
      w.z = ((const float*)&v[2])[q]; w.w = ((const float*)&v[3])[q];
      *(float4*)&Xs[(4 * jq + q) * ASTR + (r0 ^ ph)] = w;
    }
  }

  float a = alphap[0], bt = betap[0];
  float best[8];
  int bi[8];
#pragma unroll
  for (int i = 0; i < 8; i++) { best[i] = -3.0e38f; bi[i] = 0; }

  for (int st = 0; st < 2; st++) {
    if (st) __syncthreads();  // previous tile's reads complete
    // stage 128 centers x 32 k (2 reg-transposed 4x4 blocks per thread)
#pragma unroll
    for (int it = 0; it < 2; it++) {
      int idx = t + 128 * it;
      int jq = idx & 7, c0 = 4 * (idx >> 3);  // c0 in {0..124}
      int ph = ((jq >> 1) & 3) << 2;
      float4 v[4];
#pragma unroll
      for (int i = 0; i < 4; i++)
        v[i] = *(const float4*)(cp + (size_t)(st * 128 + c0 + i) * SC + 4 * jq);
#pragma unroll
      for (int q = 0; q < 4; q++) {
        float4 w;
        w.x = ((const float*)&v[0])[q]; w.y = ((const float*)&v[1])[q];
        w.z = ((const float*)&v[2])[q]; w.w = ((const float*)&v[3])[q];
        *(float4*)&Cs[(4 * jq + q) * BSTR + (c0 ^ ph)] = w;
      }
    }
    __syncthreads();

    float acc[8][8];
#pragma unroll
    for (int i = 0; i < 8; i++)
#pragma unroll
      for (int c = 0; c < 8; c++) acc[i][c] = 0.f;

    int ia0 = 4 * tr, ib0 = 4 * tc;
#pragma unroll 8
    for (int k = 0; k < 32; k++) {
      int ph = PHI(k);
      int ja = ia0 ^ ph, jb = ib0 ^ ph;
      float4 a0 = *(const float4*)&Xs[k * ASTR + ja];
      float4 a1 = *(const float4*)&Xs[k * ASTR + 32 + ja];
      float4 b0 = *(const float4*)&Cs[k * BSTR + jb];
      float4 b1 = *(const float4*)&Cs[k * BSTR + 64 + jb];
      const float* af0 = (const float*)&a0;
      const float* af1 = (const float*)&a1;
      const float* bf0 = (const float*)&b0;
      const float* bf1 = (const float*)&b1;
#pragma unroll
      for (int i = 0; i < 4; i++) {
#pragma unroll
        for (int c = 0; c < 4; c++) {
          acc[i][c]         = fmaf(af0[i], bf0[c], acc[i][c]);
          acc[i][c + 4]     = fmaf(af0[i], bf1[c], acc[i][c + 4]);
          acc[i + 4][c]     = fmaf(af1[i], bf0[c], acc[i + 4][c]);
          acc[i + 4][c + 4] = fmaf(af1[i], bf1[c], acc[i + 4][c + 4]);
        }
      }
    }

    // fold argmax (in-thread s strictly increasing across c and tiles)
#pragma unroll
    for (int i = 0; i < 8; i++) {
#pragma unroll
      for (int c = 0; c < 8; c++) {
        float tv = fmaf(a, acc[i][c], bt);
        int s = st * 128 + ((c < 4) ? (4 * tc + c) : (64 + 4 * tc + (c - 4)));
        if (tv > best[i]) { best[i] = tv; bi[i] = s; }
      }
    }
  }

#pragma unroll
  for (int i = 0; i < 8; i++) {
    int row = (i < 4) ? (4 * tr + i) : (32 + 4 * tr + (i - 4));
    float bv = best[i];
    int ix = bi[i];
#pragma unroll
    for (int m = 1; m <= 8; m <<= 1) {  // reduce across the 16 tc-lanes
      float ov = __shfl_xor(bv, m, 64);
      int oi = __shfl_xor(ix, m, 64);
      if (ov > bv || (ov == bv && oi < ix)) { bv = ov; ix = oi; }
    }
    float mv = 1.f / (1.f + expf(-bv));
    const float* cvp = cval + ((size_t)nf * Ss + ix) * SC;
    float* orow = xn + ((size_t)nI * Ll + l0 + row) * Cc + f * SC;
    orow[tc] = cvp[tc] * mv;
    orow[tc + 16] = cvp[tc + 16] * mv;
  }
}

// ---------------------------------------------------------------------------
// out = dispatched @ Wm^T + bm via bf16 MFMA, NO LDS (round-8 proven).
// ---------------------------------------------------------------------------
__global__ __launch_bounds__(256) void out_mfma_k(
    const float* __restrict__ xn, const float* __restrict__ Wm,
    const float* __restrict__ bm, float* __restrict__ out) {
  int t = threadIdx.x;
  int wave = t >> 6, lane = t & 63;
  int quad = lane >> 4, l15 = lane & 15;
  size_t m0 = (size_t)(blockIdx.x >> 1) * 128 + (wave & 1) * 64;
  int n0 = (blockIdx.x & 1) * 128 + (wave >> 1) * 64;

  f32x4 acc[4][4];
#pragma unroll
  for (int ni = 0; ni < 4; ni++) {
    float bv = bm[n0 + ni * 16 + l15];
    f32x4 ci = {bv, bv, bv, bv};
#pragma unroll
    for (int mi = 0; mi < 4; mi++) acc[mi][ni] = ci;
  }

  for (int kt = 0; kt < 8; kt++) {
    int k0 = kt * 32 + quad * 8;
    short8 Af[4], Bf[4];
#pragma unroll
    for (int mi = 0; mi < 4; mi++) {
      const float* p = xn + (m0 + mi * 16 + l15) * Cc + k0;
      float4 lo = *(const float4*)p;
      float4 hi = *(const float4*)(p + 4);
      short8 fr;
      fr[0] = (short)f2bf(lo.x); fr[1] = (short)f2bf(lo.y);
      fr[2] = (short)f2bf(lo.z); fr[3] = (short)f2bf(lo.w);
      fr[4] = (short)f2bf(hi.x); fr[5] = (short)f2bf(hi.y);
      fr[6] = (short)f2bf(hi.z); fr[7] = (short)f2bf(hi.w);
      Af[mi] = fr;
    }
#pragma unroll
    for (int ni = 0; ni < 4; ni++) {
      const float* p = Wm + (size_t)(n0 + ni * 16 + l15) * Cc + k0;
      float4 lo = *(const float4*)p;
      float4 hi = *(const float4*)(p + 4);
      short8 fr;
      fr[0] = (short)f2bf(lo.x); fr[1] = (short)f2bf(lo.y);
      fr[2] = (short)f2bf(lo.z); fr[3] = (short)f2bf(lo.w);
      fr[4] = (short)f2bf(hi.x); fr[5] = (short)f2bf(hi.y);
      fr[6] = (short)f2bf(hi.z); fr[7] = (short)f2bf(hi.w);
      Bf[ni] = fr;
    }
#pragma unroll
    for (int mi = 0; mi < 4; mi++)
#pragma unroll
      for (int ni = 0; ni < 4; ni++)
        acc[mi][ni] = __builtin_amdgcn_mfma_f32_16x16x32_bf16(
            Af[mi], Bf[ni], acc[mi][ni], 0, 0, 0);
  }

#pragma unroll
  for (int mi = 0; mi < 4; mi++) {
#pragma unroll
    for (int reg = 0; reg < 4; reg++) {
      size_t row = m0 + mi * 16 + quad * 4 + reg;
      float* orow = out + row * Cc + n0;
#pragma unroll
      for (int ni = 0; ni < 4; ni++)
        orow[ni * 16 + l15] = acc[mi][ni][reg];
    }
  }
}

// ---------------------------------------------------------------------------
extern "C" void kernel_launch(void* const* d_in, const int* in_sizes, int n_in,
                              void* d_out, int out_size, void* d_ws, size_t ws_size,
                              hipStream_t stream) {
  const float* x0      = (const float*)d_in[0];
  const float* center1 = (const float*)d_in[1];
  const float* W0      = (const float*)d_in[2];
  const float* b0      = (const float*)d_in[3];
  const float* W1      = (const float*)d_in[4];
  const float* b1      = (const float*)d_in[5];
  const float* Wm      = (const float*)d_in[6];
  const float* bm      = (const float*)d_in[7];
  const float* alpha   = (const float*)d_in[8];
  const float* beta    = (const float*)d_in[9];
  float* out = (float*)d_out;
  float* ws  = (float*)d_ws;

  float* xn   = ws;                              // 16 MB: x0p, then dispatched in-place
  float* cpn  = xn + (size_t)Nn * Ll * Cc;       // 1 MB
  float* cval = cpn + (size_t)Nn * FC * Ss * SC; // 1 MB  (total 18 MB)

  x0p_c1_k<<<dim3(576), dim3(128), 0, stream>>>(
      x0, W0, b0, center1, W1, b1, xn, cpn, cval);
  sim_k<<<dim3(32 * 64), dim3(128), 0, stream>>>(xn, cpn, cval, alpha, beta);
  out_mfma_k<<<dim3(256), dim3(256), 0, stream>>>(xn, Wm, bm, out);
}

// Round 10
// 186.857 us; speedup vs baseline: 1.0425x; 1.0425x over previous
//
#include <hip/hip_runtime.h>
#include <math.h>

// Problem constants (fixed by setup_inputs)
#define Nn 4
#define Ll 4096
#define Ss 256
#define Cc 256
#define FC 8
#define SC 32

#define ASTR 68                         // A-tile LDS stride (64 rows + pad)
#define BSTR 132                        // B-tile LDS stride (128 rows + pad)
#define PHI(k) ((((k) >> 3) & 3) << 2)  // row-XOR swizzle (const per k-octet)

typedef __attribute__((ext_vector_type(8))) short short8;   // 8 bf16 frag
typedef __attribute__((ext_vector_type(4))) float f32x4;    // MFMA acc

__device__ __forceinline__ unsigned short f2bf(float x) {   // RTNE f32->bf16
  unsigned int u = __float_as_uint(x);
  return (unsigned short)((u + 0x7FFFu + ((u >> 16) & 1u)) >> 16);
}

// ---------------------------------------------------------------------------
// k-major fp32 GEMM tile, 64x128, 128 threads (2 waves), thread 8x8.
// Thread rows {4tr+i, 32+4tr+i}, cols {cb0+4tc+c, cb0+64+4tc+c}.
// LDS word (r,k): A at k*ASTR + (r^PHI(k)), B at k*BSTR + (r^PHI(k)).
// ROUND-10 CHANGE: k-loop processes BATCHES of 4 k-steps — issue all 16
// ds_read_b128 (PHI const within an aligned 4-batch), wait once, then 256
// fma. Amortizes the LDS wait (~200cyc) over 512 VALU cyc instead of per-k.
// #pragma unroll 1 on batch & kt loops prevents full-unroll VGPR explosion
// (round-4/6 failure mode).
// ---------------------------------------------------------------------------
__device__ __forceinline__ void gemm_tile64(
    const float* __restrict__ A, const float* __restrict__ W,
    const float* __restrict__ bias, size_t row0, int cb0,
    float* __restrict__ As, float* __restrict__ Bs, int t, float acc[8][8]) {
  int tc = t & 15, tr = t >> 4;        // tr in [0,8)
  int jq = t & 7, r0s = 4 * (t >> 3);  // t>>3 in [0,16): rows r0s..r0s+3
  int phS = ((jq >> 1) & 3) << 2;      // PHI(4jq+q), q<4
  int woffA = (4 * jq) * ASTR + (r0s ^ phS);
  int woffB = (4 * jq) * BSTR + (r0s ^ phS);

  float4 bb0 = *(const float4*)&bias[cb0 + 4 * tc];
  float4 bb1 = *(const float4*)&bias[cb0 + 64 + 4 * tc];
#pragma unroll
  for (int i = 0; i < 8; i++) {
    acc[i][0] = bb0.x; acc[i][1] = bb0.y; acc[i][2] = bb0.z; acc[i][3] = bb0.w;
    acc[i][4] = bb1.x; acc[i][5] = bb1.y; acc[i][6] = bb1.z; acc[i][7] = bb1.w;
  }

  float4 pa[4], pb0[4], pb1[4];
#pragma unroll
  for (int i = 0; i < 4; i++) {
    pa[i]  = *(const float4*)(A + (row0 + r0s + i) * Cc + 4 * jq);
    pb0[i] = *(const float4*)(W + (size_t)(cb0 + r0s + i) * Cc + 4 * jq);
    pb1[i] = *(const float4*)(W + (size_t)(cb0 + 64 + r0s + i) * Cc + 4 * jq);
  }

#pragma unroll 1
  for (int kt = 0; kt < 8; kt++) {
    __syncthreads();  // reads of previous tile done before overwrite
#pragma unroll
    for (int q = 0; q < 4; q++) {
      float4 wa, w0, w1;
      wa.x = ((const float*)&pa[0])[q];  wa.y = ((const float*)&pa[1])[q];
      wa.z = ((const float*)&pa[2])[q];  wa.w = ((const float*)&pa[3])[q];
      w0.x = ((const float*)&pb0[0])[q]; w0.y = ((const float*)&pb0[1])[q];
      w0.z = ((const float*)&pb0[2])[q]; w0.w = ((const float*)&pb0[3])[q];
      w1.x = ((const float*)&pb1[0])[q]; w1.y = ((const float*)&pb1[1])[q];
      w1.z = ((const float*)&pb1[2])[q]; w1.w = ((const float*)&pb1[3])[q];
      *(float4*)&As[woffA + q * ASTR] = wa;
      *(float4*)&Bs[woffB + q * BSTR] = w0;
      *(float4*)&Bs[woffB + 64 + q * BSTR] = w1;
    }
    __syncthreads();  // staging visible
    if (kt < 7) {     // prefetch for next kt (compiler may sink; acceptable)
#pragma unroll
      for (int i = 0; i < 4; i++) {
        pa[i]  = *(const float4*)(A + (row0 + r0s + i) * Cc + (kt + 1) * 32 + 4 * jq);
        pb0[i] = *(const float4*)(W + (size_t)(cb0 + r0s + i) * Cc + (kt + 1) * 32 + 4 * jq);
        pb1[i] = *(const float4*)(W + (size_t)(cb0 + 64 + r0s + i) * Cc + (kt + 1) * 32 + 4 * jq);
      }
    }

    int ia0 = 4 * tr, ib0 = 4 * tc;
#pragma unroll 1
    for (int kb = 0; kb < 32; kb += 4) {
      int ph = PHI(kb);             // constant across the aligned 4-batch
      int ja = ia0 ^ ph, jb = ib0 ^ ph;
      float4 A0[4], A1[4], B0[4], B1[4];
#pragma unroll
      for (int u = 0; u < 4; u++) {
        const float* ab = &As[(kb + u) * ASTR];
        const float* bb = &Bs[(kb + u) * BSTR];
        A0[u] = *(const float4*)&ab[ja];
        A1[u] = *(const float4*)&ab[32 + ja];
        B0[u] = *(const float4*)&bb[jb];
        B1[u] = *(const float4*)&bb[64 + jb];
      }
#pragma unroll
      for (int u = 0; u < 4; u++) {
        const float* af0 = (const float*)&A0[u];
        const float* af1 = (const float*)&A1[u];
        const float* bf0 = (const float*)&B0[u];
        const float* bf1 = (const float*)&B1[u];
#pragma unroll
        for (int i = 0; i < 4; i++) {
#pragma unroll
          for (int c = 0; c < 4; c++) {
            acc[i][c]         = fmaf(af0[i], bf0[c], acc[i][c]);
            acc[i][c + 4]     = fmaf(af0[i], bf1[c], acc[i][c + 4]);
            acc[i + 4][c]     = fmaf(af1[i], bf0[c], acc[i + 4][c]);
            acc[i + 4][c + 4] = fmaf(af1[i], bf1[c], acc[i + 4][c + 4]);
          }
        }
      }
    }
  }
}

// ---------------------------------------------------------------------------
// Fused kernel 1. Blocks 0..511: x0p = x0 @ W0^T + b0 -> xn (64-row tiles).
// Blocks 512..575: c1 = center1 @ W1^T + b1 (M=1024,N=512) + split/norm
// epilogue -> cpn (l2-normalized point half), cval (raw value half).
// ---------------------------------------------------------------------------
__global__ __launch_bounds__(128) void x0p_c1_k(
    const float* __restrict__ x0, const float* __restrict__ W0,
    const float* __restrict__ b0, const float* __restrict__ center1,
    const float* __restrict__ W1, const float* __restrict__ b1,
    float* __restrict__ xn, float* __restrict__ cpn, float* __restrict__ cval) {
  __shared__ float As[32 * ASTR];  //  8.7 KB
  __shared__ float Bs[32 * BSTR];  // 16.9 KB
  int t = threadIdx.x;
  int tc = t & 15, tr = t >> 4;
  int b = blockIdx.x;
  float acc[8][8];

  if (b < 512) {
    size_t row0 = (size_t)(b >> 1) * 64;
    int cb0 = (b & 1) * 128;
    gemm_tile64(x0, W0, b0, row0, cb0, As, Bs, t, acc);
#pragma unroll
    for (int i = 0; i < 8; i++) {
      int r = (i < 4) ? (4 * tr + i) : (32 + 4 * tr + (i - 4));
      float4 o0, o1;
      o0.x = acc[i][0]; o0.y = acc[i][1]; o0.z = acc[i][2]; o0.w = acc[i][3];
      o1.x = acc[i][4]; o1.y = acc[i][5]; o1.z = acc[i][6]; o1.w = acc[i][7];
      float* cr = xn + (row0 + r) * Cc + cb0;
      *(float4*)(cr + 4 * tc) = o0;
      *(float4*)(cr + 64 + 4 * tc) = o1;
    }
  } else {
    int b2 = b - 512;
    size_t row0 = (size_t)(b2 >> 2) * 64;  // M=1024 (n*256+s)
    int cb0 = (b2 & 3) * 128;              // N=512
    gemm_tile64(center1, W1, b1, row0, cb0, As, Bs, t, acc);
    // cols {cb0+4tc+c} (fiber fb) / {cb0+64+4tc+c} (fiber fb+1);
    // q = 4tc+c in 0..63; point iff q<32 <=> tc<8.
    int fb = cb0 >> 6;
#pragma unroll
    for (int i = 0; i < 8; i++) {
      int r = (i < 4) ? (4 * tr + i) : (32 + 4 * tr + (i - 4));
      int crow = (int)row0 + r;
      int nI = crow >> 8, s = crow & 255;
#pragma unroll
      for (int h = 0; h < 2; h++) {
        float s0 = acc[i][4 * h + 0], s1 = acc[i][4 * h + 1];
        float s2 = acc[i][4 * h + 2], s3 = acc[i][4 * h + 3];
        float ss = s0 * s0 + s1 * s1 + s2 * s2 + s3 * s3;
        ss += __shfl_xor(ss, 1, 64);
        ss += __shfl_xor(ss, 2, 64);
        ss += __shfl_xor(ss, 4, 64);  // sums the tc-octet (point lanes tc<8)
        float rin = 1.f / fmaxf(sqrtf(ss), 1e-12f);
        int f = fb + h;
        size_t base = (((size_t)nI * FC + f) * Ss + s) * SC;
        if (tc < 8) {
          float4 o; o.x = s0 * rin; o.y = s1 * rin; o.z = s2 * rin; o.w = s3 * rin;
          *(float4*)&cpn[base + 4 * tc] = o;
        } else {
          float4 o; o.x = s0; o.y = s1; o.z = s2; o.w = s3;
          *(float4*)&cval[base + 4 * (tc - 8)] = o;
        }
      }
    }
  }
}

// ---------------------------------------------------------------------------
// sim: per block one (n,f), 64 l-rows; centers as TWO tiles of 128 looped
// in-block. 128 threads, thread 8 rows {4tr+i, 32+4tr+i} x 8 centers
// {4tc+c, 64+4tc+c} per tile. ROUND-10: G=4 k-batched LDS reads (same as
// gemm_tile64). X rows l2-normalized at staging. Argmax of a*sim+b folded
// across tiles in-thread, then 16-lane shfl_xor reduce (min-index tie).
// Gather c_value, scale by sigmoid(max), write dispatched IN PLACE over xn.
// ---------------------------------------------------------------------------
__global__ __launch_bounds__(128) void sim_k(
    float* __restrict__ xn, const float* __restrict__ cpn,
    const float* __restrict__ cval, const float* __restrict__ alphap,
    const float* __restrict__ betap) {
  __shared__ float Xs[32 * ASTR];  //  8.7 KB (rows 0..63)
  __shared__ float Cs[32 * BSTR];  // 16.9 KB (128 centers per tile)
  int t = threadIdx.x;
  int tc = t & 15, tr = t >> 4;    // tr in [0,8)
  int lt = blockIdx.x & 63;
  int nf = blockIdx.x >> 6;        // 0..31
  int f = nf & 7, nI = nf >> 3;
  int l0 = lt * 64;
  const float* cp = cpn + (size_t)nf * Ss * SC;

  // stage x rows 64x32, l2-normalized (8-lane shfl per row)
  {
    int jq = t & 7, r0 = 4 * (t >> 3);  // rows r0..r0+3
    int ph = ((jq >> 1) & 3) << 2;
    float4 v[4];
    float ssq[4];
#pragma unroll
    for (int i = 0; i < 4; i++) {
      v[i] = *(const float4*)(xn + ((size_t)nI * Ll + l0 + r0 + i) * Cc + f * SC + 4 * jq);
      ssq[i] = v[i].x * v[i].x + v[i].y * v[i].y + v[i].z * v[i].z + v[i].w * v[i].w;
    }
#pragma unroll
    for (int m = 1; m <= 4; m <<= 1)
#pragma unroll
      for (int i = 0; i < 4; i++) ssq[i] += __shfl_xor(ssq[i], m, 64);
#pragma unroll
    for (int i = 0; i < 4; i++) {
      float rin = 1.f / fmaxf(sqrtf(ssq[i]), 1e-12f);
      v[i].x *= rin; v[i].y *= rin; v[i].z *= rin; v[i].w *= rin;
    }
#pragma unroll
    for (int q = 0; q < 4; q++) {
      float4 w;
      w.x = ((const float*)&v[0])[q]; w.y = ((const float*)&v[1])[q];
      w.z = ((const float*)&v[2])[q]; w.w = ((const float*)&v[3])[q];
      *(float4*)&Xs[(4 * jq + q) * ASTR + (r0 ^ ph)] = w;
    }
  }

  float a = alphap[0], bt = betap[0];
  float best[8];
  int bi[8];
#pragma unroll
  for (int i = 0; i < 8; i++) { best[i] = -3.0e38f; bi[i] = 0; }

#pragma unroll 1
  for (int st = 0; st < 2; st++) {
    if (st) __syncthreads();  // previous tile's reads complete
    // stage 128 centers x 32 k (2 reg-transposed 4x4 blocks per thread)
#pragma unroll
    for (int it = 0; it < 2; it++) {
      int idx = t + 128 * it;
      int jq = idx & 7, c0 = 4 * (idx >> 3);  // c0 in {0..124}
      int ph = ((jq >> 1) & 3) << 2;
      float4 v[4];
#pragma unroll
      for (int i = 0; i < 4; i++)
        v[i] = *(const float4*)(cp + (size_t)(st * 128 + c0 + i) * SC + 4 * jq);
#pragma unroll
      for (int q = 0; q < 4; q++) {
        float4 w;
        w.x = ((const float*)&v[0])[q]; w.y = ((const float*)&v[1])[q];
        w.z = ((const float*)&v[2])[q]; w.w = ((const float*)&v[3])[q];
        *(float4*)&Cs[(4 * jq + q) * BSTR + (c0 ^ ph)] = w;
      }
    }
    __syncthreads();

    float acc[8][8];
#pragma unroll
    for (int i = 0; i < 8; i++)
#pragma unroll
      for (int c = 0; c < 8; c++) acc[i][c] = 0.f;

    int ia0 = 4 * tr, ib0 = 4 * tc;
#pragma unroll 1
    for (int kb = 0; kb < 32; kb += 4) {
      int ph = PHI(kb);
      int ja = ia0 ^ ph, jb = ib0 ^ ph;
      float4 A0[4], A1[4], B0[4], B1[4];
#pragma unroll
      for (int u = 0; u < 4; u++) {
        const float* ab = &Xs[(kb + u) * ASTR];
        const float* bb = &Cs[(kb + u) * BSTR];
        A0[u] = *(const float4*)&ab[ja];
        A1[u] = *(const float4*)&ab[32 + ja];
        B0[u] = *(const float4*)&bb[jb];
        B1[u] = *(const float4*)&bb[64 + jb];
      }
#pragma unroll
      for (int u = 0; u < 4; u++) {
        const float* af0 = (const float*)&A0[u];
        const float* af1 = (const float*)&A1[u];
        const float* bf0 = (const float*)&B0[u];
        const float* bf1 = (const float*)&B1[u];
#pragma unroll
        for (int i = 0; i < 4; i++) {
#pragma unroll
          for (int c = 0; c < 4; c++) {
            acc[i][c]         = fmaf(af0[i], bf0[c], acc[i][c]);
            acc[i][c + 4]     = fmaf(af0[i], bf1[c], acc[i][c + 4]);
            acc[i + 4][c]     = fmaf(af1[i], bf0[c], acc[i + 4][c]);
            acc[i + 4][c + 4] = fmaf(af1[i], bf1[c], acc[i + 4][c + 4]);
          }
        }
      }
    }

    // fold argmax (in-thread s strictly increasing across c and tiles)
#pragma unroll
    for (int i = 0; i < 8; i++) {
#pragma unroll
      for (int c = 0; c < 8; c++) {
        float tv = fmaf(a, acc[i][c], bt);
        int s = st * 128 + ((c < 4) ? (4 * tc + c) : (64 + 4 * tc + (c - 4)));
        if (tv > best[i]) { best[i] = tv; bi[i] = s; }
      }
    }
  }

#pragma unroll
  for (int i = 0; i < 8; i++) {
    int row = (i < 4) ? (4 * tr + i) : (32 + 4 * tr + (i - 4));
    float bv = best[i];
    int ix = bi[i];
#pragma unroll
    for (int m = 1; m <= 8; m <<= 1) {  // reduce across the 16 tc-lanes
      float ov = __shfl_xor(bv, m, 64);
      int oi = __shfl_xor(ix, m, 64);
      if (ov > bv || (ov == bv && oi < ix)) { bv = ov; ix = oi; }
    }
    float mv = 1.f / (1.f + expf(-bv));
    const float* cvp = cval + ((size_t)nf * Ss + ix) * SC;
    float* orow = xn + ((size_t)nI * Ll + l0 + row) * Cc + f * SC;
    orow[tc] = cvp[tc] * mv;
    orow[tc + 16] = cvp[tc + 16] * mv;
  }
}

// ---------------------------------------------------------------------------
// out = dispatched @ Wm^T + bm via bf16 MFMA, NO LDS (round-8 proven).
// ---------------------------------------------------------------------------
__global__ __launch_bounds__(256) void out_mfma_k(
    const float* __restrict__ xn, const float* __restrict__ Wm,
    const float* __restrict__ bm, float* __restrict__ out) {
  int t = threadIdx.x;
  int wave = t >> 6, lane = t & 63;
  int quad = lane >> 4, l15 = lane & 15;
  size_t m0 = (size_t)(blockIdx.x >> 1) * 128 + (wave & 1) * 64;
  int n0 = (blockIdx.x & 1) * 128 + (wave >> 1) * 64;

  f32x4 acc[4][4];
#pragma unroll
  for (int ni = 0; ni < 4; ni++) {
    float bv = bm[n0 + ni * 16 + l15];
    f32x4 ci = {bv, bv, bv, bv};
#pragma unroll
    for (int mi = 0; mi < 4; mi++) acc[mi][ni] = ci;
  }

  for (int kt = 0; kt < 8; kt++) {
    int k0 = kt * 32 + quad * 8;
    short8 Af[4], Bf[4];
#pragma unroll
    for (int mi = 0; mi < 4; mi++) {
      const float* p = xn + (m0 + mi * 16 + l15) * Cc + k0;
      float4 lo = *(const float4*)p;
      float4 hi = *(const float4*)(p + 4);
      short8 fr;
      fr[0] = (short)f2bf(lo.x); fr[1] = (short)f2bf(lo.y);
      fr[2] = (short)f2bf(lo.z); fr[3] = (short)f2bf(lo.w);
      fr[4] = (short)f2bf(hi.x); fr[5] = (short)f2bf(hi.y);
      fr[6] = (short)f2bf(hi.z); fr[7] = (short)f2bf(hi.w);
      Af[mi] = fr;
    }
#pragma unroll
    for (int ni = 0; ni < 4; ni++) {
      const float* p = Wm + (size_t)(n0 + ni * 16 + l15) * Cc + k0;
      float4 lo = *(const float4*)p;
      float4 hi = *(const float4*)(p + 4);
      short8 fr;
      fr[0] = (short)f2bf(lo.x); fr[1] = (short)f2bf(lo.y);
      fr[2] = (short)f2bf(lo.z); fr[3] = (short)f2bf(lo.w);
      fr[4] = (short)f2bf(hi.x); fr[5] = (short)f2bf(hi.y);
      fr[6] = (short)f2bf(hi.z); fr[7] = (short)f2bf(hi.w);
      Bf[ni] = fr;
    }
#pragma unroll
    for (int mi = 0; mi < 4; mi++)
#pragma unroll
      for (int ni = 0; ni < 4; ni++)
        acc[mi][ni] = __builtin_amdgcn_mfma_f32_16x16x32_bf16(
            Af[mi], Bf[ni], acc[mi][ni], 0, 0, 0);
  }

#pragma unroll
  for (int mi = 0; mi < 4; mi++) {
#pragma unroll
    for (int reg = 0; reg < 4; reg++) {
      size_t row = m0 + mi * 16 + quad * 4 + reg;
      float* orow = out + row * Cc + n0;
#pragma unroll
      for (int ni = 0; ni < 4; ni++)
        orow[ni * 16 + l15] = acc[mi][ni][reg];
    }
  }
}

// ---------------------------------------------------------------------------
extern "C" void kernel_launch(void* const* d_in, const int* in_sizes, int n_in,
                              void* d_out, int out_size, void* d_ws, size_t ws_size,
                              hipStream_t stream) {
  const float* x0      = (const float*)d_in[0];
  const float* center1 = (const float*)d_in[1];
  const float* W0      = (const float*)d_in[2];
  const float* b0      = (const float*)d_in[3];
  const float* W1      = (const float*)d_in[4];
  const float* b1      = (const float*)d_in[5];
  const float* Wm      = (const float*)d_in[6];
  const float* bm      = (const float*)d_in[7];
  const float* alpha   = (const float*)d_in[8];
  const float* beta    = (const float*)d_in[9];
  float* out = (float*)d_out;
  float* ws  = (float*)d_ws;

  float* xn   = ws;                              // 16 MB: x0p, then dispatched in-place
  float* cpn  = xn + (size_t)Nn * Ll * Cc;       // 1 MB
  float* cval = cpn + (size_t)Nn * FC * Ss * SC; // 1 MB  (total 18 MB)

  x0p_c1_k<<<dim3(576), dim3(128), 0, stream>>>(
      x0, W0, b0, center1, W1, b1, xn, cpn, cval);
  sim_k<<<dim3(32 * 64), dim3(128), 0, stream>>>(xn, cpn, cval, alpha, beta);
  out_mfma_k<<<dim3(256), dim3(256), 0, stream>>>(xn, Wm, bm, out);
}